// Round 13
// baseline (1556.051 us; speedup 1.0000x reference)
//
#include <hip/hip_runtime.h>

#define V_N 100000
#define J_N 24
#define NB_N 10
#define NP_N 207
#define FLAT_P 621
#define FACE_I 600000
#define CHUNKS 50
#define CHUNK_V 2000
#define K1_BLK 1172       // ceil(300000/256)
#define F_BLK  587        // ceil(150000/256)
#define PA_REP 80
#define PB_REP 80
#define PC_REP 100
#define PD_REP 8

__device__ __constant__ int PARENT_D[24] = {
    -1, 0, 0, 0, 1, 2, 3, 4, 5, 6, 7, 8, 9, 9, 9, 12, 13, 14, 16, 17, 18, 19, 20, 21
};

__device__ __forceinline__ float wave_sum64(float x) {
    float t;
    t = __int_as_float(__builtin_amdgcn_update_dpp(0, __float_as_int(x), 0x111, 0xf, 0xf, true)); x += t;
    t = __int_as_float(__builtin_amdgcn_update_dpp(0, __float_as_int(x), 0x112, 0xf, 0xf, true)); x += t;
    t = __int_as_float(__builtin_amdgcn_update_dpp(0, __float_as_int(x), 0x114, 0xf, 0xf, true)); x += t;
    t = __int_as_float(__builtin_amdgcn_update_dpp(0, __float_as_int(x), 0x118, 0xf, 0xf, true)); x += t;
    t = __int_as_float(__builtin_amdgcn_update_dpp(0, __float_as_int(x), 0x142, 0xa, 0xf, true)); x += t;
    t = __int_as_float(__builtin_amdgcn_update_dpp(0, __float_as_int(x), 0x143, 0xc, 0xf, true)); x += t;
    return __int_as_float(__builtin_amdgcn_readlane(__float_as_int(x), 63));
}

// ---------------- kA: shape blend + faces copy (REAL, unchanged) ----------------
__global__ __launch_bounds__(256) void kA_shape_faces(const float* __restrict__ shapedirs,
                                                      const float* __restrict__ vtemp,
                                                      const float* __restrict__ beta,
                                                      float* __restrict__ vshaped,
                                                      const int4* __restrict__ faces4,
                                                      float* __restrict__ out) {
    int b = blockIdx.x;
    if (b < K1_BLK) {
        int i = b * 256 + threadIdx.x;
        if (i >= V_N * 3) return;
        const float2* sd2 = reinterpret_cast<const float2*>(shapedirs + (size_t)i * NB_N);
        float2 p0 = sd2[0], p1 = sd2[1], p2 = sd2[2], p3 = sd2[3], p4 = sd2[4];
        float acc = vtemp[i];
        acc += p0.x * beta[0] + p0.y * beta[1];
        acc += p1.x * beta[2] + p1.y * beta[3];
        acc += p2.x * beta[4] + p2.y * beta[5];
        acc += p3.x * beta[6] + p3.y * beta[7];
        acc += p4.x * beta[8] + p4.y * beta[9];
        vshaped[i] = acc;
    } else {
        int i = (b - K1_BLK) * 256 + threadIdx.x;
        if (i < FACE_I / 4) {
            int4 f = faces4[i];
            float4* fdst = reinterpret_cast<float4*>(out + 300000);
            fdst[i] = make_float4((float)f.x, (float)f.y, (float)f.z, (float)f.w);
        }
    }
}

// ---------------- kB: partial GEMV (REAL, unchanged) ----------------
__global__ __launch_bounds__(256) void kB_partial(const float* __restrict__ Jreg,
                                                  const float* __restrict__ vshaped,
                                                  float* __restrict__ partials) {
    int c = blockIdx.x, j = blockIdx.y;
    int t = threadIdx.x;
    const float* row = Jreg + (size_t)j * V_N + (size_t)c * CHUNK_V;
    const float* vs  = vshaped + (size_t)c * CHUNK_V * 3;
    float s0 = 0.f, s1 = 0.f, s2 = 0.f;
    for (int i = t; i < CHUNK_V; i += 256) {
        float w = row[i];
        s0 += w * vs[i * 3 + 0];
        s1 += w * vs[i * 3 + 1];
        s2 += w * vs[i * 3 + 2];
    }
    for (int off = 32; off > 0; off >>= 1) {
        s0 += __shfl_xor(s0, off, 64);
        s1 += __shfl_xor(s1, off, 64);
        s2 += __shfl_xor(s2, off, 64);
    }
    __shared__ float ls[3][4];
    int wv = t >> 6;
    if ((t & 63) == 0) { ls[0][wv] = s0; ls[1][wv] = s1; ls[2][wv] = s2; }
    __syncthreads();
    if (t == 0) {
        float* p = partials + ((size_t)j * CHUNKS + c) * 3;
        p[0] = ls[0][0] + ls[0][1] + ls[0][2] + ls[0][3];
        p[1] = ls[1][0] + ls[1][1] + ls[1][2] + ls[1][3];
        p[2] = ls[2][0] + ls[2][1] + ls[2][2] + ls[2][3];
    }
}

// ---------------- kC: Jts reduce + Rodrigues + lrot + FK + A (REAL, unchanged) ----------------
__global__ __launch_bounds__(64) void kC_fk(const float* __restrict__ pose,
                                            const float* __restrict__ partials,
                                            float* __restrict__ ws_lrot,
                                            float* __restrict__ ws_A) {
    __shared__ float R[24][9];
    __shared__ float G[24][12];
    __shared__ float Jts[24][3];
    int t = threadIdx.x;
    for (int u = t; u < 72; u += 64) {
        int j = u / 3, d = u % 3;
        float s = 0.f;
        for (int c = 0; c < CHUNKS; ++c) s += partials[((size_t)j * CHUNKS + c) * 3 + d];
        (&Jts[0][0])[u] = s;
    }
    if (t < 24) {
        float x = pose[t * 3 + 0], y = pose[t * 3 + 1], z = pose[t * 3 + 2];
        float th = sqrtf(x * x + y * y + z * z) + 1e-8f;
        float inv = 1.0f / th;
        float rx = x * inv, ry = y * inv, rz = z * inv;
        float c = cosf(th), s = sinf(th), ic = 1.0f - c;
        R[t][0] = c + ic * rx * rx;      R[t][1] = ic * rx * ry - s * rz;  R[t][2] = ic * rx * rz + s * ry;
        R[t][3] = ic * ry * rx + s * rz; R[t][4] = c + ic * ry * ry;       R[t][5] = ic * ry * rz - s * rx;
        R[t][6] = ic * rz * rx - s * ry; R[t][7] = ic * rz * ry + s * rx;  R[t][8] = c + ic * rz * rz;
    }
    __syncthreads();
    for (int f = t; f < 640; f += 64) {
        float val = 0.0f;
        if (f < FLAT_P) {
            int p = f % NP_N;
            int j = 1 + p / 9;
            int e = p % 9;
            val = R[j][e] - ((e == 0 || e == 4 || e == 8) ? 1.0f : 0.0f);
        }
        ws_lrot[f] = val;
    }
    if (t < 12) {
        int r = t >> 2, c = t & 3;
        G[0][t] = (c < 3) ? R[0][r * 3 + c] : Jts[0][r];
    }
    __syncthreads();
    for (int i = 1; i < J_N; ++i) {
        int p = PARENT_D[i];
        if (t < 12) {
            int r = t >> 2, c = t & 3;
            float sum = (c == 3) ? G[p][r * 4 + 3] : 0.0f;
            #pragma unroll
            for (int k = 0; k < 3; ++k) {
                float loc = (c < 3) ? R[i][k * 3 + c] : (Jts[i][k] - Jts[p][k]);
                sum += G[p][r * 4 + k] * loc;
            }
            G[i][t] = sum;
        }
        __syncthreads();
    }
    for (int u = t; u < 72; u += 64) {
        int j = u / 3, r = u % 3;
        float g0 = G[j][r * 4 + 0], g1 = G[j][r * 4 + 1], g2 = G[j][r * 4 + 2], g3 = G[j][r * 4 + 3];
        float corr = g0 * Jts[j][0] + g1 * Jts[j][1] + g2 * Jts[j][2];
        ws_A[j * 12 + r * 4 + 0] = g0;
        ws_A[j * 12 + r * 4 + 1] = g1;
        ws_A[j * 12 + r * 4 + 2] = g2;
        ws_A[j * 12 + r * 4 + 3] = g3 - corr;
    }
}

// ---------------- kD: pose blend + skinning (REAL, unchanged) ----------------
__global__ __launch_bounds__(256) void kD_main(const float* __restrict__ posedirs,
                                               const float* __restrict__ weights,
                                               const float* __restrict__ vshaped,
                                               const float* __restrict__ ws_lrot,
                                               const float* __restrict__ ws_A,
                                               const float* __restrict__ trans,
                                               float* __restrict__ out) {
    __shared__ float sL[640];
    __shared__ float sA[288];
    int tid = threadIdx.x;
    for (int i = tid; i < 640; i += 256) sL[i] = ws_lrot[i];
    for (int i = tid; i < 288; i += 256) sA[i] = ws_A[i];
    __syncthreads();

    int lane = tid & 63;
    int v = blockIdx.x * 4 + (tid >> 6);
    if (v >= V_N) return;

    const float* pd = posedirs + (size_t)v * FLAT_P;
    float a0 = 0.f, a1 = 0.f, a2 = 0.f;
    #pragma unroll
    for (int k = 0; k < 10; ++k) {
        int f = lane + k * 64;
        if (f < FLAT_P) {
            float val = pd[f] * sL[f];
            if (f < 207)      a0 += val;
            else if (f < 414) a1 += val;
            else              a2 += val;
        }
    }
    float vp0 = wave_sum64(a0) + vshaped[v * 3 + 0];
    float vp1 = wave_sum64(a1) + vshaped[v * 3 + 1];
    float vp2 = wave_sum64(a2) + vshaped[v * 3 + 2];

    float r0 = 0.f, r1 = 0.f, r2 = 0.f;
    if (lane < J_N) {
        float w = weights[(size_t)v * J_N + lane];
        const float* A = &sA[lane * 12];
        r0 = w * (A[0] * vp0 + A[1] * vp1 + A[2]  * vp2 + A[3]);
        r1 = w * (A[4] * vp0 + A[5] * vp1 + A[6]  * vp2 + A[7]);
        r2 = w * (A[8] * vp0 + A[9] * vp1 + A[10] * vp2 + A[11]);
    }
    float s0 = wave_sum64(r0);
    float s1 = wave_sum64(r1);
    float s2 = wave_sum64(r2);

    if (lane < 3) {
        float res = (lane == 0) ? s0 : (lane == 1) ? s1 : s2;
        out[v * 3 + lane] = res + trans[lane];
    }
}

// ================= PROBES: real bodies x REPS, writing ws scratch =================
__global__ __launch_bounds__(256) void pA(const float* __restrict__ shapedirs,
                                          const float* __restrict__ vtemp,
                                          const float* __restrict__ beta,
                                          const int4* __restrict__ faces4,
                                          float* __restrict__ scr) {
    int b = blockIdx.x;
    #pragma unroll 1
    for (int rep = 0; rep < PA_REP; ++rep) {
        if (b < K1_BLK) {
            int i = b * 256 + threadIdx.x;
            if (i < V_N * 3) {
                const float2* sd2 = reinterpret_cast<const float2*>(shapedirs + (size_t)i * NB_N);
                float2 p0 = sd2[0], p1 = sd2[1], p2 = sd2[2], p3 = sd2[3], p4 = sd2[4];
                float acc = vtemp[i];
                acc += p0.x * beta[0] + p0.y * beta[1];
                acc += p1.x * beta[2] + p1.y * beta[3];
                acc += p2.x * beta[4] + p2.y * beta[5];
                acc += p3.x * beta[6] + p3.y * beta[7];
                acc += p4.x * beta[8] + p4.y * beta[9];
                scr[i] = acc;
            }
        } else {
            int i = (b - K1_BLK) * 256 + threadIdx.x;
            if (i < FACE_I / 4) {
                int4 f = faces4[i];
                float4* fdst = reinterpret_cast<float4*>(scr);   // scratch, not out
                fdst[i] = make_float4((float)f.x, (float)f.y, (float)f.z, (float)f.w);
            }
        }
        asm volatile("" ::: "memory");
    }
}

__global__ __launch_bounds__(256) void pB(const float* __restrict__ Jreg,
                                          const float* __restrict__ vshaped,
                                          float* __restrict__ scr) {
    int c = blockIdx.x, j = blockIdx.y;
    int t = threadIdx.x;
    #pragma unroll 1
    for (int rep = 0; rep < PB_REP; ++rep) {
        const float* row = Jreg + (size_t)j * V_N + (size_t)c * CHUNK_V;
        const float* vs  = vshaped + (size_t)c * CHUNK_V * 3;
        float s0 = 0.f, s1 = 0.f, s2 = 0.f;
        for (int i = t; i < CHUNK_V; i += 256) {
            float w = row[i];
            s0 += w * vs[i * 3 + 0];
            s1 += w * vs[i * 3 + 1];
            s2 += w * vs[i * 3 + 2];
        }
        for (int off = 32; off > 0; off >>= 1) {
            s0 += __shfl_xor(s0, off, 64);
            s1 += __shfl_xor(s1, off, 64);
            s2 += __shfl_xor(s2, off, 64);
        }
        __shared__ float ls[3][4];
        int wv = t >> 6;
        if ((t & 63) == 0) { ls[0][wv] = s0; ls[1][wv] = s1; ls[2][wv] = s2; }
        __syncthreads();
        if (t == 0) {
            float* p = scr + ((size_t)j * CHUNKS + c) * 3;
            p[0] = ls[0][0] + ls[0][1] + ls[0][2] + ls[0][3];
            p[1] = ls[1][0] + ls[1][1] + ls[1][2] + ls[1][3];
            p[2] = ls[2][0] + ls[2][1] + ls[2][2] + ls[2][3];
        }
        __syncthreads();
        asm volatile("" ::: "memory");
    }
}

__global__ __launch_bounds__(64) void pC(const float* __restrict__ pose,
                                         const float* __restrict__ partials,
                                         float* __restrict__ scr_lrot,
                                         float* __restrict__ scr_A) {
    __shared__ float R[24][9];
    __shared__ float G[24][12];
    __shared__ float Jts[24][3];
    int t = threadIdx.x;
    #pragma unroll 1
    for (int rep = 0; rep < PC_REP; ++rep) {
        for (int u = t; u < 72; u += 64) {
            int j = u / 3, d = u % 3;
            float s = 0.f;
            for (int c = 0; c < CHUNKS; ++c) s += partials[((size_t)j * CHUNKS + c) * 3 + d];
            (&Jts[0][0])[u] = s;
        }
        if (t < 24) {
            float x = pose[t * 3 + 0], y = pose[t * 3 + 1], z = pose[t * 3 + 2];
            float th = sqrtf(x * x + y * y + z * z) + 1e-8f;
            float inv = 1.0f / th;
            float rx = x * inv, ry = y * inv, rz = z * inv;
            float c = cosf(th), s = sinf(th), ic = 1.0f - c;
            R[t][0] = c + ic * rx * rx;      R[t][1] = ic * rx * ry - s * rz;  R[t][2] = ic * rx * rz + s * ry;
            R[t][3] = ic * ry * rx + s * rz; R[t][4] = c + ic * ry * ry;       R[t][5] = ic * ry * rz - s * rx;
            R[t][6] = ic * rz * rx - s * ry; R[t][7] = ic * rz * ry + s * rx;  R[t][8] = c + ic * rz * rz;
        }
        __syncthreads();
        for (int f = t; f < 640; f += 64) {
            float val = 0.0f;
            if (f < FLAT_P) {
                int p = f % NP_N;
                int j = 1 + p / 9;
                int e = p % 9;
                val = R[j][e] - ((e == 0 || e == 4 || e == 8) ? 1.0f : 0.0f);
            }
            scr_lrot[f] = val;
        }
        if (t < 12) {
            int r = t >> 2, c = t & 3;
            G[0][t] = (c < 3) ? R[0][r * 3 + c] : Jts[0][r];
        }
        __syncthreads();
        for (int i = 1; i < J_N; ++i) {
            int p = PARENT_D[i];
            if (t < 12) {
                int r = t >> 2, c = t & 3;
                float sum = (c == 3) ? G[p][r * 4 + 3] : 0.0f;
                #pragma unroll
                for (int k = 0; k < 3; ++k) {
                    float loc = (c < 3) ? R[i][k * 3 + c] : (Jts[i][k] - Jts[p][k]);
                    sum += G[p][r * 4 + k] * loc;
                }
                G[i][t] = sum;
            }
            __syncthreads();
        }
        for (int u = t; u < 72; u += 64) {
            int j = u / 3, r = u % 3;
            float g0 = G[j][r * 4 + 0], g1 = G[j][r * 4 + 1], g2 = G[j][r * 4 + 2], g3 = G[j][r * 4 + 3];
            float corr = g0 * Jts[j][0] + g1 * Jts[j][1] + g2 * Jts[j][2];
            scr_A[j * 12 + r * 4 + 0] = g0;
            scr_A[j * 12 + r * 4 + 1] = g1;
            scr_A[j * 12 + r * 4 + 2] = g2;
            scr_A[j * 12 + r * 4 + 3] = g3 - corr;
        }
        __syncthreads();
        asm volatile("" ::: "memory");
    }
}

__global__ __launch_bounds__(256) void pD(const float* __restrict__ posedirs,
                                          const float* __restrict__ weights,
                                          const float* __restrict__ vshaped,
                                          const float* __restrict__ ws_lrot,
                                          const float* __restrict__ ws_A,
                                          const float* __restrict__ trans,
                                          float* __restrict__ scr) {
    __shared__ float sL[640];
    __shared__ float sA[288];
    int tid = threadIdx.x;
    for (int i = tid; i < 640; i += 256) sL[i] = ws_lrot[i];
    for (int i = tid; i < 288; i += 256) sA[i] = ws_A[i];
    __syncthreads();

    int lane = tid & 63;
    int v = blockIdx.x * 4 + (tid >> 6);
    if (v >= V_N) return;

    #pragma unroll 1
    for (int rep = 0; rep < PD_REP; ++rep) {
        const float* pd = posedirs + (size_t)v * FLAT_P;
        float a0 = 0.f, a1 = 0.f, a2 = 0.f;
        #pragma unroll
        for (int k = 0; k < 10; ++k) {
            int f = lane + k * 64;
            if (f < FLAT_P) {
                float val = pd[f] * sL[f];
                if (f < 207)      a0 += val;
                else if (f < 414) a1 += val;
                else              a2 += val;
            }
        }
        float vp0 = wave_sum64(a0) + vshaped[v * 3 + 0];
        float vp1 = wave_sum64(a1) + vshaped[v * 3 + 1];
        float vp2 = wave_sum64(a2) + vshaped[v * 3 + 2];

        float r0 = 0.f, r1 = 0.f, r2 = 0.f;
        if (lane < J_N) {
            float w = weights[(size_t)v * J_N + lane];
            const float* A = &sA[lane * 12];
            r0 = w * (A[0] * vp0 + A[1] * vp1 + A[2]  * vp2 + A[3]);
            r1 = w * (A[4] * vp0 + A[5] * vp1 + A[6]  * vp2 + A[7]);
            r2 = w * (A[8] * vp0 + A[9] * vp1 + A[10] * vp2 + A[11]);
        }
        float s0 = wave_sum64(r0);
        float s1 = wave_sum64(r1);
        float s2 = wave_sum64(r2);

        if (lane < 3) {
            float res = (lane == 0) ? s0 : (lane == 1) ? s1 : s2;
            scr[v * 3 + lane] = res + trans[lane];
        }
        asm volatile("" ::: "memory");
    }
}

extern "C" void kernel_launch(void* const* d_in, const int* in_sizes, int n_in,
                              void* d_out, int out_size, void* d_ws, size_t ws_size,
                              hipStream_t stream) {
    const float* beta      = (const float*)d_in[0];
    const float* pose      = (const float*)d_in[1];
    const float* trans     = (const float*)d_in[2];
    const float* shapedirs = (const float*)d_in[3];
    const float* v_template= (const float*)d_in[4];
    const float* J_reg     = (const float*)d_in[5];
    const float* posedirs  = (const float*)d_in[6];
    const float* weights   = (const float*)d_in[7];
    const int*   faces     = (const int*)d_in[8];

    float* out = (float*)d_out;

    // ws layout (floats)
    float* ws       = (float*)d_ws;
    float* vshaped  = ws;                 // 300000
    float* ws_lrot  = ws + 300080;        // 640
    float* ws_A     = ws + 300720;        // 288
    float* partials = ws + 301008;        // 3600
    float* scr      = ws + 400000;        // shared probe scratch (<=300000 floats)

    // ---- real pipeline (R12 structure, unchanged) ----
    kA_shape_faces<<<K1_BLK + F_BLK, 256, 0, stream>>>(shapedirs, v_template, beta, vshaped,
                                                       (const int4*)faces, out);
    kB_partial<<<dim3(CHUNKS, J_N), 256, 0, stream>>>(J_reg, vshaped, partials);
    kC_fk<<<1, 64, 0, stream>>>(pose, partials, ws_lrot, ws_A);
    kD_main<<<(V_N + 3) / 4, 256, 0, stream>>>(posedirs, weights, vshaped, ws_lrot, ws_A, trans, out);

    // ---- probes (measurement only; all writes go to scr) ----
    pA<<<K1_BLK + F_BLK, 256, 0, stream>>>(shapedirs, v_template, beta, (const int4*)faces, scr);
    pB<<<dim3(CHUNKS, J_N), 256, 0, stream>>>(J_reg, vshaped, scr);
    pC<<<1, 64, 0, stream>>>(pose, partials, scr, scr + 1024);
    pD<<<(V_N + 3) / 4, 256, 0, stream>>>(posedirs, weights, vshaped, ws_lrot, ws_A, trans, scr);
}

// Round 14
// 98.952 us; speedup vs baseline: 15.7254x; 15.7254x over previous
//
#include <hip/hip_runtime.h>

#define V_N 100000
#define J_N 24
#define NB_N 10
#define NP_N 207
#define FLAT_P 621
#define FACE_I 600000
#define CHUNKS 50
#define CHUNK_V 2000
#define K1_BLK 1172       // ceil(300000/256)
#define F_BLK  587        // ceil(150000/256)
#define TBL_T 192
#define TBL_N (7 * TBL_T) // 1344

__device__ __constant__ int PARENT_D[24] = {
    -1, 0, 0, 0, 1, 2, 3, 4, 5, 6, 7, 8, 9, 9, 9, 12, 13, 14, 16, 17, 18, 19, 20, 21
};

__device__ __forceinline__ float wave_sum64(float x) {
    float t;
    t = __int_as_float(__builtin_amdgcn_update_dpp(0, __float_as_int(x), 0x111, 0xf, 0xf, true)); x += t;
    t = __int_as_float(__builtin_amdgcn_update_dpp(0, __float_as_int(x), 0x112, 0xf, 0xf, true)); x += t;
    t = __int_as_float(__builtin_amdgcn_update_dpp(0, __float_as_int(x), 0x114, 0xf, 0xf, true)); x += t;
    t = __int_as_float(__builtin_amdgcn_update_dpp(0, __float_as_int(x), 0x118, 0xf, 0xf, true)); x += t;
    t = __int_as_float(__builtin_amdgcn_update_dpp(0, __float_as_int(x), 0x142, 0xa, 0xf, true)); x += t;
    t = __int_as_float(__builtin_amdgcn_update_dpp(0, __float_as_int(x), 0x143, 0xc, 0xf, true)); x += t;
    return __int_as_float(__builtin_amdgcn_readlane(__float_as_int(x), 63));
}

// ---------------- kA: shape blend + faces copy (unchanged) ----------------
__global__ __launch_bounds__(256) void kA_shape_faces(const float* __restrict__ shapedirs,
                                                      const float* __restrict__ vtemp,
                                                      const float* __restrict__ beta,
                                                      float* __restrict__ vshaped,
                                                      const int4* __restrict__ faces4,
                                                      float* __restrict__ out) {
    int b = blockIdx.x;
    if (b < K1_BLK) {
        int i = b * 256 + threadIdx.x;
        if (i >= V_N * 3) return;
        const float2* sd2 = reinterpret_cast<const float2*>(shapedirs + (size_t)i * NB_N);
        float2 p0 = sd2[0], p1 = sd2[1], p2 = sd2[2], p3 = sd2[3], p4 = sd2[4];
        float acc = vtemp[i];
        acc += p0.x * beta[0] + p0.y * beta[1];
        acc += p1.x * beta[2] + p1.y * beta[3];
        acc += p2.x * beta[4] + p2.y * beta[5];
        acc += p3.x * beta[6] + p3.y * beta[7];
        acc += p4.x * beta[8] + p4.y * beta[9];
        vshaped[i] = acc;
    } else {
        int i = (b - K1_BLK) * 256 + threadIdx.x;
        if (i < FACE_I / 4) {
            int4 f = faces4[i];
            float4* fdst = reinterpret_cast<float4*>(out + 300000);
            fdst[i] = make_float4((float)f.x, (float)f.y, (float)f.z, (float)f.w);
        }
    }
}

// ---------------- kB: partial GEMV — TRANSPOSED partials write [c][72] ----------------
__global__ __launch_bounds__(256) void kB_partial(const float* __restrict__ Jreg,
                                                  const float* __restrict__ vshaped,
                                                  float* __restrict__ partials) {
    int c = blockIdx.x, j = blockIdx.y;
    int t = threadIdx.x;
    const float* row = Jreg + (size_t)j * V_N + (size_t)c * CHUNK_V;
    const float* vs  = vshaped + (size_t)c * CHUNK_V * 3;
    float s0 = 0.f, s1 = 0.f, s2 = 0.f;
    for (int i = t; i < CHUNK_V; i += 256) {
        float w = row[i];
        s0 += w * vs[i * 3 + 0];
        s1 += w * vs[i * 3 + 1];
        s2 += w * vs[i * 3 + 2];
    }
    for (int off = 32; off > 0; off >>= 1) {
        s0 += __shfl_xor(s0, off, 64);
        s1 += __shfl_xor(s1, off, 64);
        s2 += __shfl_xor(s2, off, 64);
    }
    __shared__ float ls[3][4];
    int wv = t >> 6;
    if ((t & 63) == 0) { ls[0][wv] = s0; ls[1][wv] = s1; ls[2][wv] = s2; }
    __syncthreads();
    if (t == 0) {
        float* p = partials + (size_t)c * 72 + j * 3;   // [c][j*3+d]
        p[0] = ls[0][0] + ls[0][1] + ls[0][2] + ls[0][3];
        p[1] = ls[1][0] + ls[1][1] + ls[1][2] + ls[1][3];
        p[2] = ls[2][0] + ls[2][1] + ls[2][2] + ls[2][3];
    }
}

// ---------------- kC: parallel Jts reduce + Rodrigues + delta-table + FK + A ----------------
// 128 threads. Thread u<72: Jts[u] = sum_c partials[c*72+u] (50 INDEPENDENT loads).
// Builds delta-decimated table ws_sd[7*192]: sd[d][tt] = lrot[4*tt + d - 3] (0 outside).
__global__ __launch_bounds__(128) void kC_fk(const float* __restrict__ pose,
                                             const float* __restrict__ partials,
                                             float* __restrict__ ws_sd,
                                             float* __restrict__ ws_A) {
    __shared__ float R[24][9];
    __shared__ float G[24][12];
    __shared__ float Jts[24][3];
    int t = threadIdx.x;
    if (t < 72) {
        float s = 0.f;
        #pragma unroll
        for (int c = 0; c < CHUNKS; ++c) s += partials[c * 72 + t];
        (&Jts[0][0])[t] = s;
    }
    if (t < 24) {
        float x = pose[t * 3 + 0], y = pose[t * 3 + 1], z = pose[t * 3 + 2];
        float th = sqrtf(x * x + y * y + z * z) + 1e-8f;
        float inv = 1.0f / th;
        float rx = x * inv, ry = y * inv, rz = z * inv;
        float c = cosf(th), s = sinf(th), ic = 1.0f - c;
        R[t][0] = c + ic * rx * rx;      R[t][1] = ic * rx * ry - s * rz;  R[t][2] = ic * rx * rz + s * ry;
        R[t][3] = ic * ry * rx + s * rz; R[t][4] = c + ic * ry * ry;       R[t][5] = ic * ry * rz - s * rx;
        R[t][6] = ic * rz * rx - s * ry; R[t][7] = ic * rz * ry + s * rx;  R[t][8] = c + ic * rz * rz;
    }
    __syncthreads();
    // delta-decimated lrot table (R5-proven): idx = d*192 + tt, val = lrot[4*tt + d - 3] or 0
    for (int idx = t; idx < TBL_N; idx += 128) {
        int d  = idx / TBL_T;
        int tt = idx % TBL_T;
        int f  = 4 * tt + d - 3;
        float val = 0.0f;
        if (f >= 0 && f < FLAT_P) {
            int p = f % NP_N;
            int j = 1 + p / 9;
            int e = p % 9;
            val = R[j][e] - ((e == 0 || e == 4 || e == 8) ? 1.0f : 0.0f);
        }
        ws_sd[idx] = val;
    }
    if (t < 12) {
        int r = t >> 2, c = t & 3;
        G[0][t] = (c < 3) ? R[0][r * 3 + c] : Jts[0][r];
    }
    __syncthreads();
    for (int i = 1; i < J_N; ++i) {
        int p = PARENT_D[i];
        if (t < 12) {
            int r = t >> 2, c = t & 3;
            float sum = (c == 3) ? G[p][r * 4 + 3] : 0.0f;
            #pragma unroll
            for (int k = 0; k < 3; ++k) {
                float loc = (c < 3) ? R[i][k * 3 + c] : (Jts[i][k] - Jts[p][k]);
                sum += G[p][r * 4 + k] * loc;
            }
            G[i][t] = sum;
        }
        __syncthreads();
    }
    if (t < 72) {
        int j = t / 3, r = t % 3;
        float g0 = G[j][r * 4 + 0], g1 = G[j][r * 4 + 1], g2 = G[j][r * 4 + 2], g3 = G[j][r * 4 + 3];
        float corr = g0 * Jts[j][0] + g1 * Jts[j][1] + g2 * Jts[j][2];
        ws_A[j * 12 + r * 4 + 0] = g0;
        ws_A[j * 12 + r * 4 + 1] = g1;
        ws_A[j * 12 + r * 4 + 2] = g2;
        ws_A[j * 12 + r * 4 + 3] = g3 - corr;
    }
}

// ---------------- kD: pose blend + skinning — float4 stream + delta-table ----------------
// Wave per vertex; row = 621 floats spans exactly 156 aligned float4 slots.
// Element e of slot t -> local coeff f = 4t + e - bd (bd = row_start & 3);
// sD[(e+3-bd)*192 + t] == lrot[f] (zero-padded). t stride-1 across lanes: conflict-free.
__global__ __launch_bounds__(256) void kD_main(const float* __restrict__ posedirs,
                                               const float* __restrict__ weights,
                                               const float* __restrict__ vshaped,
                                               const float* __restrict__ ws_sd,
                                               const float* __restrict__ ws_A,
                                               const float* __restrict__ trans,
                                               float* __restrict__ out) {
    __shared__ float sD[TBL_N];
    __shared__ float sA[288];
    int tid = threadIdx.x;
    for (int i = tid; i < TBL_N; i += 256) sD[i] = ws_sd[i];
    for (int i = tid; i < 288; i += 256) sA[i] = ws_A[i];
    __syncthreads();

    int lane = tid & 63;
    int v = blockIdx.x * 4 + (tid >> 6);   // grid exactly V_N/4

    int row_start = v * FLAT_P;
    int bd = row_start & 3;
    const float4* pbase = reinterpret_cast<const float4*>(posedirs) + (row_start >> 2);
    int sbase = (3 - bd) * TBL_T;

    float a0 = 0.f, a1 = 0.f, a2 = 0.f;
    {   // k=0: f in [-3,255] -> boundary 207 only (f<0 hits table zeros)
        int t = lane;
        float4 p = pbase[t];
        const float* pf = reinterpret_cast<const float*>(&p);
        int f0 = 4 * t - bd;
        #pragma unroll
        for (int e = 0; e < 4; ++e) {
            float val = pf[e] * sD[sbase + e * TBL_T + t];
            bool c = (f0 + e) < 207;
            a0 += c ? val : 0.0f;
            a1 += c ? 0.0f : val;
        }
    }
    {   // k=1: f in [253,511] -> boundary 414 only
        int t = lane + 64;
        float4 p = pbase[t];
        const float* pf = reinterpret_cast<const float*>(&p);
        int f0 = 4 * t - bd;
        #pragma unroll
        for (int e = 0; e < 4; ++e) {
            float val = pf[e] * sD[sbase + e * TBL_T + t];
            bool c = (f0 + e) < 414;
            a1 += c ? val : 0.0f;
            a2 += c ? 0.0f : val;
        }
    }
    if (lane < 28) {   // k=2: f in [509,623] -> all bucket 2 (table zero-pads past 620)
        int t = lane + 128;
        float4 p = pbase[t];
        const float* pf = reinterpret_cast<const float*>(&p);
        #pragma unroll
        for (int e = 0; e < 4; ++e) {
            a2 += pf[e] * sD[sbase + e * TBL_T + t];
        }
    }

    float vp0 = wave_sum64(a0) + vshaped[v * 3 + 0];
    float vp1 = wave_sum64(a1) + vshaped[v * 3 + 1];
    float vp2 = wave_sum64(a2) + vshaped[v * 3 + 2];

    float r0 = 0.f, r1 = 0.f, r2 = 0.f;
    if (lane < J_N) {
        float w = weights[(size_t)v * J_N + lane];
        const float* A = &sA[lane * 12];
        r0 = w * (A[0] * vp0 + A[1] * vp1 + A[2]  * vp2 + A[3]);
        r1 = w * (A[4] * vp0 + A[5] * vp1 + A[6]  * vp2 + A[7]);
        r2 = w * (A[8] * vp0 + A[9] * vp1 + A[10] * vp2 + A[11]);
    }
    float s0 = wave_sum64(r0);
    float s1 = wave_sum64(r1);
    float s2 = wave_sum64(r2);

    if (lane < 3) {
        float res = (lane == 0) ? s0 : (lane == 1) ? s1 : s2;
        out[v * 3 + lane] = res + trans[lane];
    }
}

extern "C" void kernel_launch(void* const* d_in, const int* in_sizes, int n_in,
                              void* d_out, int out_size, void* d_ws, size_t ws_size,
                              hipStream_t stream) {
    const float* beta      = (const float*)d_in[0];
    const float* pose      = (const float*)d_in[1];
    const float* trans     = (const float*)d_in[2];
    const float* shapedirs = (const float*)d_in[3];
    const float* v_template= (const float*)d_in[4];
    const float* J_reg     = (const float*)d_in[5];
    const float* posedirs  = (const float*)d_in[6];
    const float* weights   = (const float*)d_in[7];
    const int*   faces     = (const int*)d_in[8];

    float* out = (float*)d_out;

    // ws layout (floats)
    float* ws       = (float*)d_ws;
    float* vshaped  = ws;                 // 300000
    float* ws_sd    = ws + 300080;        // 1344
    float* ws_A     = ws + 301504;        // 288
    float* partials = ws + 301808;        // [c][72] = 3600

    kA_shape_faces<<<K1_BLK + F_BLK, 256, 0, stream>>>(shapedirs, v_template, beta, vshaped,
                                                       (const int4*)faces, out);
    kB_partial<<<dim3(CHUNKS, J_N), 256, 0, stream>>>(J_reg, vshaped, partials);
    kC_fk<<<1, 128, 0, stream>>>(pose, partials, ws_sd, ws_A);
    kD_main<<<V_N / 4, 256, 0, stream>>>(posedirs, weights, vshaped, ws_sd, ws_A, trans, out);
}

// Round 15
// 84.870 us; speedup vs baseline: 18.3344x; 1.1659x over previous
//
#include <hip/hip_runtime.h>

#define V_N 100000
#define J_N 24
#define NB_N 10
#define NP_N 207
#define FLAT_P 621
#define FACE_I 600000
#define CHUNKS 50
#define CHUNK_V 2000
#define K1_BLK 1172       // ceil(300000/256)
#define F_BLK  587        // ceil(150000/256)

__device__ __constant__ int PARENT_D[24] = {
    -1, 0, 0, 0, 1, 2, 3, 4, 5, 6, 7, 8, 9, 9, 9, 12, 13, 14, 16, 17, 18, 19, 20, 21
};

__device__ __forceinline__ float wave_sum64(float x) {
    float t;
    t = __int_as_float(__builtin_amdgcn_update_dpp(0, __float_as_int(x), 0x111, 0xf, 0xf, true)); x += t;
    t = __int_as_float(__builtin_amdgcn_update_dpp(0, __float_as_int(x), 0x112, 0xf, 0xf, true)); x += t;
    t = __int_as_float(__builtin_amdgcn_update_dpp(0, __float_as_int(x), 0x114, 0xf, 0xf, true)); x += t;
    t = __int_as_float(__builtin_amdgcn_update_dpp(0, __float_as_int(x), 0x118, 0xf, 0xf, true)); x += t;
    t = __int_as_float(__builtin_amdgcn_update_dpp(0, __float_as_int(x), 0x142, 0xa, 0xf, true)); x += t;
    t = __int_as_float(__builtin_amdgcn_update_dpp(0, __float_as_int(x), 0x143, 0xc, 0xf, true)); x += t;
    return __int_as_float(__builtin_amdgcn_readlane(__float_as_int(x), 63));
}

// ---------------- kA: shape blend + faces copy (unchanged, R12-proven) ----------------
__global__ __launch_bounds__(256) void kA_shape_faces(const float* __restrict__ shapedirs,
                                                      const float* __restrict__ vtemp,
                                                      const float* __restrict__ beta,
                                                      float* __restrict__ vshaped,
                                                      const int4* __restrict__ faces4,
                                                      float* __restrict__ out) {
    int b = blockIdx.x;
    if (b < K1_BLK) {
        int i = b * 256 + threadIdx.x;
        if (i >= V_N * 3) return;
        const float2* sd2 = reinterpret_cast<const float2*>(shapedirs + (size_t)i * NB_N);
        float2 p0 = sd2[0], p1 = sd2[1], p2 = sd2[2], p3 = sd2[3], p4 = sd2[4];
        float acc = vtemp[i];
        acc += p0.x * beta[0] + p0.y * beta[1];
        acc += p1.x * beta[2] + p1.y * beta[3];
        acc += p2.x * beta[4] + p2.y * beta[5];
        acc += p3.x * beta[6] + p3.y * beta[7];
        acc += p4.x * beta[8] + p4.y * beta[9];
        vshaped[i] = acc;
    } else {
        int i = (b - K1_BLK) * 256 + threadIdx.x;
        if (i < FACE_I / 4) {
            int4 f = faces4[i];
            float4* fdst = reinterpret_cast<float4*>(out + 300000);
            fdst[i] = make_float4((float)f.x, (float)f.y, (float)f.z, (float)f.w);
        }
    }
}

// ---------------- kB: partial GEMV — TRANSPOSED partials write [c][72] (R14-proven) ----------------
__global__ __launch_bounds__(256) void kB_partial(const float* __restrict__ Jreg,
                                                  const float* __restrict__ vshaped,
                                                  float* __restrict__ partials) {
    int c = blockIdx.x, j = blockIdx.y;
    int t = threadIdx.x;
    const float* row = Jreg + (size_t)j * V_N + (size_t)c * CHUNK_V;
    const float* vs  = vshaped + (size_t)c * CHUNK_V * 3;
    float s0 = 0.f, s1 = 0.f, s2 = 0.f;
    for (int i = t; i < CHUNK_V; i += 256) {
        float w = row[i];
        s0 += w * vs[i * 3 + 0];
        s1 += w * vs[i * 3 + 1];
        s2 += w * vs[i * 3 + 2];
    }
    for (int off = 32; off > 0; off >>= 1) {
        s0 += __shfl_xor(s0, off, 64);
        s1 += __shfl_xor(s1, off, 64);
        s2 += __shfl_xor(s2, off, 64);
    }
    __shared__ float ls[3][4];
    int wv = t >> 6;
    if ((t & 63) == 0) { ls[0][wv] = s0; ls[1][wv] = s1; ls[2][wv] = s2; }
    __syncthreads();
    if (t == 0) {
        float* p = partials + (size_t)c * 72 + j * 3;   // [c][j*3+d]
        p[0] = ls[0][0] + ls[0][1] + ls[0][2] + ls[0][3];
        p[1] = ls[1][0] + ls[1][1] + ls[1][2] + ls[1][3];
        p[2] = ls[2][0] + ls[2][1] + ls[2][2] + ls[2][3];
    }
}

// ---------------- kC: parallel Jts reduce (independent loads) + Rodrigues + 640-lrot + FK + A ----------------
// 128 threads. Thread u<72: Jts[u] = sum_c partials[c*72+u] — 50 INDEPENDENT stride-72 loads.
__global__ __launch_bounds__(128) void kC_fk(const float* __restrict__ pose,
                                             const float* __restrict__ partials,
                                             float* __restrict__ ws_lrot,
                                             float* __restrict__ ws_A) {
    __shared__ float R[24][9];
    __shared__ float G[24][12];
    __shared__ float Jts[24][3];
    int t = threadIdx.x;
    if (t < 72) {
        float s = 0.f;
        #pragma unroll
        for (int c = 0; c < CHUNKS; ++c) s += partials[c * 72 + t];
        (&Jts[0][0])[t] = s;
    }
    if (t < 24) {
        float x = pose[t * 3 + 0], y = pose[t * 3 + 1], z = pose[t * 3 + 2];
        float th = sqrtf(x * x + y * y + z * z) + 1e-8f;
        float inv = 1.0f / th;
        float rx = x * inv, ry = y * inv, rz = z * inv;
        float c = cosf(th), s = sinf(th), ic = 1.0f - c;
        R[t][0] = c + ic * rx * rx;      R[t][1] = ic * rx * ry - s * rz;  R[t][2] = ic * rx * rz + s * ry;
        R[t][3] = ic * ry * rx + s * rz; R[t][4] = c + ic * ry * ry;       R[t][5] = ic * ry * rz - s * rx;
        R[t][6] = ic * rz * rx - s * ry; R[t][7] = ic * rz * ry + s * rx;  R[t][8] = c + ic * rz * rz;
    }
    __syncthreads();
    // lrotmin table extended to 640: table[f] = lrotmin[f % 207] (f<621), else 0
    for (int f = t; f < 640; f += 128) {
        float val = 0.0f;
        if (f < FLAT_P) {
            int p = f % NP_N;
            int j = 1 + p / 9;
            int e = p % 9;
            val = R[j][e] - ((e == 0 || e == 4 || e == 8) ? 1.0f : 0.0f);
        }
        ws_lrot[f] = val;
    }
    if (t < 12) {
        int r = t >> 2, c = t & 3;
        G[0][t] = (c < 3) ? R[0][r * 3 + c] : Jts[0][r];
    }
    __syncthreads();
    for (int i = 1; i < J_N; ++i) {
        int p = PARENT_D[i];
        if (t < 12) {
            int r = t >> 2, c = t & 3;
            float sum = (c == 3) ? G[p][r * 4 + 3] : 0.0f;
            #pragma unroll
            for (int k = 0; k < 3; ++k) {
                float loc = (c < 3) ? R[i][k * 3 + c] : (Jts[i][k] - Jts[p][k]);
                sum += G[p][r * 4 + k] * loc;
            }
            G[i][t] = sum;
        }
        __syncthreads();
    }
    if (t < 72) {
        int j = t / 3, r = t % 3;
        float g0 = G[j][r * 4 + 0], g1 = G[j][r * 4 + 1], g2 = G[j][r * 4 + 2], g3 = G[j][r * 4 + 3];
        float corr = g0 * Jts[j][0] + g1 * Jts[j][1] + g2 * Jts[j][2];
        ws_A[j * 12 + r * 4 + 0] = g0;
        ws_A[j * 12 + r * 4 + 1] = g1;
        ws_A[j * 12 + r * 4 + 2] = g2;
        ws_A[j * 12 + r * 4 + 3] = g3 - corr;
    }
}

// ---------------- kD: pose blend + skinning (R12 dword version, UNCHANGED) ----------------
__global__ __launch_bounds__(256) void kD_main(const float* __restrict__ posedirs,
                                               const float* __restrict__ weights,
                                               const float* __restrict__ vshaped,
                                               const float* __restrict__ ws_lrot,
                                               const float* __restrict__ ws_A,
                                               const float* __restrict__ trans,
                                               float* __restrict__ out) {
    __shared__ float sL[640];
    __shared__ float sA[288];
    int tid = threadIdx.x;
    for (int i = tid; i < 640; i += 256) sL[i] = ws_lrot[i];
    for (int i = tid; i < 288; i += 256) sA[i] = ws_A[i];
    __syncthreads();

    int lane = tid & 63;
    int v = blockIdx.x * 4 + (tid >> 6);
    if (v >= V_N) return;

    const float* pd = posedirs + (size_t)v * FLAT_P;
    float a0 = 0.f, a1 = 0.f, a2 = 0.f;
    #pragma unroll
    for (int k = 0; k < 10; ++k) {
        int f = lane + k * 64;
        if (f < FLAT_P) {
            float val = pd[f] * sL[f];
            if (f < 207)      a0 += val;
            else if (f < 414) a1 += val;
            else              a2 += val;
        }
    }
    float vp0 = wave_sum64(a0) + vshaped[v * 3 + 0];
    float vp1 = wave_sum64(a1) + vshaped[v * 3 + 1];
    float vp2 = wave_sum64(a2) + vshaped[v * 3 + 2];

    float r0 = 0.f, r1 = 0.f, r2 = 0.f;
    if (lane < J_N) {
        float w = weights[(size_t)v * J_N + lane];
        const float* A = &sA[lane * 12];
        r0 = w * (A[0] * vp0 + A[1] * vp1 + A[2]  * vp2 + A[3]);
        r1 = w * (A[4] * vp0 + A[5] * vp1 + A[6]  * vp2 + A[7]);
        r2 = w * (A[8] * vp0 + A[9] * vp1 + A[10] * vp2 + A[11]);
    }
    float s0 = wave_sum64(r0);
    float s1 = wave_sum64(r1);
    float s2 = wave_sum64(r2);

    if (lane < 3) {
        float res = (lane == 0) ? s0 : (lane == 1) ? s1 : s2;
        out[v * 3 + lane] = res + trans[lane];
    }
}

extern "C" void kernel_launch(void* const* d_in, const int* in_sizes, int n_in,
                              void* d_out, int out_size, void* d_ws, size_t ws_size,
                              hipStream_t stream) {
    const float* beta      = (const float*)d_in[0];
    const float* pose      = (const float*)d_in[1];
    const float* trans     = (const float*)d_in[2];
    const float* shapedirs = (const float*)d_in[3];
    const float* v_template= (const float*)d_in[4];
    const float* J_reg     = (const float*)d_in[5];
    const float* posedirs  = (const float*)d_in[6];
    const float* weights   = (const float*)d_in[7];
    const int*   faces     = (const int*)d_in[8];

    float* out = (float*)d_out;

    // ws layout (floats)
    float* ws       = (float*)d_ws;
    float* vshaped  = ws;                 // 300000
    float* ws_lrot  = ws + 300080;        // 640
    float* ws_A     = ws + 300720;        // 288
    float* partials = ws + 301008;        // [c][72] = 3600

    kA_shape_faces<<<K1_BLK + F_BLK, 256, 0, stream>>>(shapedirs, v_template, beta, vshaped,
                                                       (const int4*)faces, out);
    kB_partial<<<dim3(CHUNKS, J_N), 256, 0, stream>>>(J_reg, vshaped, partials);
    kC_fk<<<1, 128, 0, stream>>>(pose, partials, ws_lrot, ws_A);
    kD_main<<<(V_N + 3) / 4, 256, 0, stream>>>(posedirs, weights, vshaped, ws_lrot, ws_A, trans, out);
}

// Round 16
// 81.171 us; speedup vs baseline: 19.1700x; 1.0456x over previous
//
#include <hip/hip_runtime.h>

#define V_N 100000
#define J_N 24
#define NB_N 10
#define NP_N 207
#define FLAT_P 621
#define FACE_I 600000
#define CHUNKS 50
#define CHUNK_V 2000
#define K1_BLK 1172       // ceil(300000/256)
#define F_BLK  587        // ceil(150000/256)

__device__ __constant__ int PARENT_D[24] = {
    -1, 0, 0, 0, 1, 2, 3, 4, 5, 6, 7, 8, 9, 9, 9, 12, 13, 14, 16, 17, 18, 19, 20, 21
};

typedef __attribute__((address_space(3))) void lds_void;
typedef __attribute__((address_space(1))) void glb_void;

__device__ __forceinline__ float wave_sum64(float x) {
    float t;
    t = __int_as_float(__builtin_amdgcn_update_dpp(0, __float_as_int(x), 0x111, 0xf, 0xf, true)); x += t;
    t = __int_as_float(__builtin_amdgcn_update_dpp(0, __float_as_int(x), 0x112, 0xf, 0xf, true)); x += t;
    t = __int_as_float(__builtin_amdgcn_update_dpp(0, __float_as_int(x), 0x114, 0xf, 0xf, true)); x += t;
    t = __int_as_float(__builtin_amdgcn_update_dpp(0, __float_as_int(x), 0x118, 0xf, 0xf, true)); x += t;
    t = __int_as_float(__builtin_amdgcn_update_dpp(0, __float_as_int(x), 0x142, 0xa, 0xf, true)); x += t;
    t = __int_as_float(__builtin_amdgcn_update_dpp(0, __float_as_int(x), 0x143, 0xc, 0xf, true)); x += t;
    return __int_as_float(__builtin_amdgcn_readlane(__float_as_int(x), 63));
}

// ---------------- kA: shape blend + faces copy (R12-proven, unchanged) ----------------
__global__ __launch_bounds__(256) void kA_shape_faces(const float* __restrict__ shapedirs,
                                                      const float* __restrict__ vtemp,
                                                      const float* __restrict__ beta,
                                                      float* __restrict__ vshaped,
                                                      const int4* __restrict__ faces4,
                                                      float* __restrict__ out) {
    int b = blockIdx.x;
    if (b < K1_BLK) {
        int i = b * 256 + threadIdx.x;
        if (i >= V_N * 3) return;
        const float2* sd2 = reinterpret_cast<const float2*>(shapedirs + (size_t)i * NB_N);
        float2 p0 = sd2[0], p1 = sd2[1], p2 = sd2[2], p3 = sd2[3], p4 = sd2[4];
        float acc = vtemp[i];
        acc += p0.x * beta[0] + p0.y * beta[1];
        acc += p1.x * beta[2] + p1.y * beta[3];
        acc += p2.x * beta[4] + p2.y * beta[5];
        acc += p3.x * beta[6] + p3.y * beta[7];
        acc += p4.x * beta[8] + p4.y * beta[9];
        vshaped[i] = acc;
    } else {
        int i = (b - K1_BLK) * 256 + threadIdx.x;
        if (i < FACE_I / 4) {
            int4 f = faces4[i];
            float4* fdst = reinterpret_cast<float4*>(out + 300000);
            fdst[i] = make_float4((float)f.x, (float)f.y, (float)f.z, (float)f.w);
        }
    }
}

// ---------------- kB: partial GEMV — transposed partials [c][72] (R14-proven) ----------------
__global__ __launch_bounds__(256) void kB_partial(const float* __restrict__ Jreg,
                                                  const float* __restrict__ vshaped,
                                                  float* __restrict__ partials) {
    int c = blockIdx.x, j = blockIdx.y;
    int t = threadIdx.x;
    const float* row = Jreg + (size_t)j * V_N + (size_t)c * CHUNK_V;
    const float* vs  = vshaped + (size_t)c * CHUNK_V * 3;
    float s0 = 0.f, s1 = 0.f, s2 = 0.f;
    for (int i = t; i < CHUNK_V; i += 256) {
        float w = row[i];
        s0 += w * vs[i * 3 + 0];
        s1 += w * vs[i * 3 + 1];
        s2 += w * vs[i * 3 + 2];
    }
    for (int off = 32; off > 0; off >>= 1) {
        s0 += __shfl_xor(s0, off, 64);
        s1 += __shfl_xor(s1, off, 64);
        s2 += __shfl_xor(s2, off, 64);
    }
    __shared__ float ls[3][4];
    int wv = t >> 6;
    if ((t & 63) == 0) { ls[0][wv] = s0; ls[1][wv] = s1; ls[2][wv] = s2; }
    __syncthreads();
    if (t == 0) {
        float* p = partials + (size_t)c * 72 + j * 3;
        p[0] = ls[0][0] + ls[0][1] + ls[0][2] + ls[0][3];
        p[1] = ls[1][0] + ls[1][1] + ls[1][2] + ls[1][3];
        p[2] = ls[2][0] + ls[2][1] + ls[2][2] + ls[2][3];
    }
}

// ---------------- kC: parallel Jts reduce + Rodrigues + 640-lrot + FK + A (R15-proven) ----------------
__global__ __launch_bounds__(128) void kC_fk(const float* __restrict__ pose,
                                             const float* __restrict__ partials,
                                             float* __restrict__ ws_lrot,
                                             float* __restrict__ ws_A) {
    __shared__ float R[24][9];
    __shared__ float G[24][12];
    __shared__ float Jts[24][3];
    int t = threadIdx.x;
    if (t < 72) {
        float s = 0.f;
        #pragma unroll
        for (int c = 0; c < CHUNKS; ++c) s += partials[c * 72 + t];
        (&Jts[0][0])[t] = s;
    }
    if (t < 24) {
        float x = pose[t * 3 + 0], y = pose[t * 3 + 1], z = pose[t * 3 + 2];
        float th = sqrtf(x * x + y * y + z * z) + 1e-8f;
        float inv = 1.0f / th;
        float rx = x * inv, ry = y * inv, rz = z * inv;
        float c = cosf(th), s = sinf(th), ic = 1.0f - c;
        R[t][0] = c + ic * rx * rx;      R[t][1] = ic * rx * ry - s * rz;  R[t][2] = ic * rx * rz + s * ry;
        R[t][3] = ic * ry * rx + s * rz; R[t][4] = c + ic * ry * ry;       R[t][5] = ic * ry * rz - s * rx;
        R[t][6] = ic * rz * rx - s * ry; R[t][7] = ic * rz * ry + s * rx;  R[t][8] = c + ic * rz * rz;
    }
    __syncthreads();
    for (int f = t; f < 640; f += 128) {
        float val = 0.0f;
        if (f < FLAT_P) {
            int p = f % NP_N;
            int j = 1 + p / 9;
            int e = p % 9;
            val = R[j][e] - ((e == 0 || e == 4 || e == 8) ? 1.0f : 0.0f);
        }
        ws_lrot[f] = val;
    }
    if (t < 12) {
        int r = t >> 2, c = t & 3;
        G[0][t] = (c < 3) ? R[0][r * 3 + c] : Jts[0][r];
    }
    __syncthreads();
    for (int i = 1; i < J_N; ++i) {
        int p = PARENT_D[i];
        if (t < 12) {
            int r = t >> 2, c = t & 3;
            float sum = (c == 3) ? G[p][r * 4 + 3] : 0.0f;
            #pragma unroll
            for (int k = 0; k < 3; ++k) {
                float loc = (c < 3) ? R[i][k * 3 + c] : (Jts[i][k] - Jts[p][k]);
                sum += G[p][r * 4 + k] * loc;
            }
            G[i][t] = sum;
        }
        __syncthreads();
    }
    if (t < 72) {
        int j = t / 3, r = t % 3;
        float g0 = G[j][r * 4 + 0], g1 = G[j][r * 4 + 1], g2 = G[j][r * 4 + 2], g3 = G[j][r * 4 + 3];
        float corr = g0 * Jts[j][0] + g1 * Jts[j][1] + g2 * Jts[j][2];
        ws_A[j * 12 + r * 4 + 0] = g0;
        ws_A[j * 12 + r * 4 + 1] = g1;
        ws_A[j * 12 + r * 4 + 2] = g2;
        ws_A[j * 12 + r * 4 + 3] = g3 - corr;
    }
}

// ---------------- kD: pose blend + skinning — direct-to-LDS DMA staging ----------------
// Block = 4 vertices = 9936 B of posedirs, 16B-aligned for every block (9936 = 621*16).
// Staged via global_load_lds width=16: 10 instrs/block (1 KB each; chunk 9 = 45 lanes),
// linear LDS dest (lane-order contiguous = row-major rows back-to-back). Compute is
// the R12-proven dword logic reading LDS (stride-1, 2-way aliasing = free).
__global__ __launch_bounds__(256) void kD_main(const float* __restrict__ posedirs,
                                               const float* __restrict__ weights,
                                               const float* __restrict__ vshaped,
                                               const float* __restrict__ ws_lrot,
                                               const float* __restrict__ ws_A,
                                               const float* __restrict__ trans,
                                               float* __restrict__ out) {
    __shared__ __align__(16) float sP[4 * FLAT_P];   // 9936 B
    __shared__ float sL[640];
    __shared__ float sA[288];
    int tid = threadIdx.x;
    int lane = tid & 63;
    int w = tid >> 6;

    // issue DMA first so it overlaps the sL/sA loads
    const char* gbase = reinterpret_cast<const char*>(posedirs) + (size_t)blockIdx.x * 9936;
    char* lbase = reinterpret_cast<char*>(sP);
    #pragma unroll
    for (int k = 0; k < 3; ++k) {
        int chunk = w + k * 4;                 // waves 0..3 cover chunks 0..9
        if (chunk < 10) {
            int nbytes_lanes = (chunk == 9) ? 45 : 64;   // chunk 9 = 720 B
            if (lane < nbytes_lanes) {
                const void* g = gbase + chunk * 1024 + lane * 16;
                __builtin_amdgcn_global_load_lds((const glb_void*)g,
                                                 (lds_void*)(lbase + chunk * 1024),
                                                 16, 0, 0);
            }
        }
    }
    for (int i = tid; i < 640; i += 256) sL[i] = ws_lrot[i];
    for (int i = tid; i < 288; i += 256) sA[i] = ws_A[i];
    __syncthreads();   // compiler drains vmcnt before barrier -> sP ready

    int v = blockIdx.x * 4 + w;               // grid exactly V_N/4

    const float* pd = sP + w * FLAT_P;
    float a0 = 0.f, a1 = 0.f, a2 = 0.f;
    #pragma unroll
    for (int k = 0; k < 10; ++k) {
        int f = lane + k * 64;
        if (f < FLAT_P) {
            float val = pd[f] * sL[f];
            if (f < 207)      a0 += val;
            else if (f < 414) a1 += val;
            else              a2 += val;
        }
    }
    float vp0 = wave_sum64(a0) + vshaped[v * 3 + 0];
    float vp1 = wave_sum64(a1) + vshaped[v * 3 + 1];
    float vp2 = wave_sum64(a2) + vshaped[v * 3 + 2];

    float r0 = 0.f, r1 = 0.f, r2 = 0.f;
    if (lane < J_N) {
        float wgt = weights[(size_t)v * J_N + lane];
        const float* A = &sA[lane * 12];
        r0 = wgt * (A[0] * vp0 + A[1] * vp1 + A[2]  * vp2 + A[3]);
        r1 = wgt * (A[4] * vp0 + A[5] * vp1 + A[6]  * vp2 + A[7]);
        r2 = wgt * (A[8] * vp0 + A[9] * vp1 + A[10] * vp2 + A[11]);
    }
    float s0 = wave_sum64(r0);
    float s1 = wave_sum64(r1);
    float s2 = wave_sum64(r2);

    if (lane < 3) {
        float res = (lane == 0) ? s0 : (lane == 1) ? s1 : s2;
        out[v * 3 + lane] = res + trans[lane];
    }
}

extern "C" void kernel_launch(void* const* d_in, const int* in_sizes, int n_in,
                              void* d_out, int out_size, void* d_ws, size_t ws_size,
                              hipStream_t stream) {
    const float* beta      = (const float*)d_in[0];
    const float* pose      = (const float*)d_in[1];
    const float* trans     = (const float*)d_in[2];
    const float* shapedirs = (const float*)d_in[3];
    const float* v_template= (const float*)d_in[4];
    const float* J_reg     = (const float*)d_in[5];
    const float* posedirs  = (const float*)d_in[6];
    const float* weights   = (const float*)d_in[7];
    const int*   faces     = (const int*)d_in[8];

    float* out = (float*)d_out;

    // ws layout (floats)
    float* ws       = (float*)d_ws;
    float* vshaped  = ws;                 // 300000
    float* ws_lrot  = ws + 300080;        // 640
    float* ws_A     = ws + 300720;        // 288
    float* partials = ws + 301008;        // [c][72] = 3600

    kA_shape_faces<<<K1_BLK + F_BLK, 256, 0, stream>>>(shapedirs, v_template, beta, vshaped,
                                                       (const int4*)faces, out);
    kB_partial<<<dim3(CHUNKS, J_N), 256, 0, stream>>>(J_reg, vshaped, partials);
    kC_fk<<<1, 128, 0, stream>>>(pose, partials, ws_lrot, ws_A);
    kD_main<<<V_N / 4, 256, 0, stream>>>(posedirs, weights, vshaped, ws_lrot, ws_A, trans, out);
}